// Round 2
// baseline (994.524 us; speedup 1.0000x reference)
//
#include <hip/hip_runtime.h>
#include <stdint.h>

// SparseUvuTensorProduct on MI355X.
// B=32768 rows, IN_DIM=2048, OUT_DIM=2432, MUL=128.
// Groups: g0 = path(d=1,mode0); g1..g3 = (mode0 path, mode1 path) pairs sharing the
// same x1 region (d=3,5,7). Each block: TB=16 rows of one group.
//
// v3 (this round): conservative register-dot restructure on top of the VERIFIED v1.
//  - staging loops and mode1 GEMM (A=scal, B=W1 -> mixed1[b][u] in LDS): verbatim v1.
//  - mode0: MFMA output D[m=u][n=b] stays in registers; lane (l16,kg) owns b=l16,
//    u=u0+r (u0 = subtile+kg*4) — the layout v1's tmp write+read round-trip verifies.
//    Per-dd dot with x1 in registers -> tmp LDS + 2 barriers/dd GONE (15 -> 2).
//  - x1 loaded ONCE per lane (4D contiguous floats, scalar form, compiler-merged),
//    reused by mode0 dot and mode1 epilogue.
//  - epilogues per-lane, canonical scalar index form (contiguous runs -> merged).
//  - LDS 51.7KB -> 43.2KB.

#define IN_DIM 2048
#define OUT_DIM 2432
#define TB 16
#define SROW 136        // LDS row stride (bf16 elems) for x2s/scal
#define PLANE 2184      // LDS dd-plane stride for x2s: 16*136+8 (breaks bank aliasing)
#define TPAD 129        // fp32 row stride for mixed1

using bf16x8 = __attribute__((ext_vector_type(8))) short;  // 8 bf16 in 4 VGPRs
using f32x4  = __attribute__((ext_vector_type(4))) float;

__device__ __forceinline__ short f2bf(float f) {
  uint32_t u = __float_as_uint(f);
  uint32_t r = (u + 0x7fffu + ((u >> 16) & 1u)) >> 16;
  return (short)r;
}

__device__ __forceinline__ bf16x8 pack8(float4 lo, float4 hi) {
  bf16x8 r;
  r[0] = f2bf(lo.x); r[1] = f2bf(lo.y); r[2] = f2bf(lo.z); r[3] = f2bf(lo.w);
  r[4] = f2bf(hi.x); r[5] = f2bf(hi.y); r[6] = f2bf(hi.z); r[7] = f2bf(hi.w);
  return r;
}

template <int D, bool HASM1>
__device__ __forceinline__ void run_group(
    const float* __restrict__ x1, const float* __restrict__ x2,
    const float* __restrict__ w, const float* __restrict__ mask,
    float* __restrict__ out,
    int tile, int rs, int outs0, int w0off, int outs1, int w1off, float inv,
    short* x2s, short* scal, float* mixed1)
{
  const int t   = threadIdx.x;
  const int L   = t & 63;
  const int wid = t >> 6;        // wave id 0..3
  const int l16 = L & 15;
  const int kg  = L >> 4;        // k-group 0..3 (8 k's each)
  const int b0  = tile * TB;

  // ---- stage x2v tile -> LDS as bf16 [dd][b][v]  (VERBATIM v1)
  for (int i = t; i < TB * 128 * D; i += 256) {
    int b  = i / (128 * D);
    int c  = i - b * (128 * D);
    int v  = c / D;
    int dd = c - v * D;
    float val = x2[(size_t)(b0 + b) * IN_DIM + rs + c];
    x2s[dd * PLANE + b * SROW + v] = f2bf(val);
  }
  if (HASM1) {
    // mode1 scalars = x2[:, 0:128]  (VERBATIM v1)
    for (int i = t; i < TB * 128; i += 256) {
      int b = i >> 7, v = i & 127;
      scal[b * SROW + v] = f2bf(x2[(size_t)(b0 + b) * IN_DIM + v]);
    }
  }
  __syncthreads();

  // ---- mode1 GEMM: mixed1[b,u] = sum_v scal[b,v] * W1[u,v]  (VERBATIM v1)
  if (HASM1) {
    bf16x8 a4[4];
#pragma unroll
    for (int k = 0; k < 4; k++)
      a4[k] = *(const bf16x8*)&scal[l16 * SROW + kg * 8 + k * 32];
#pragma unroll
    for (int ti = 0; ti < 2; ti++) {
      int ut = (wid * 2 + ti) * 16 + l16;   // this lane's u (B-operand n index)
      f32x4 acc = {0.f, 0.f, 0.f, 0.f};
#pragma unroll
      for (int k = 0; k < 4; k++) {
        const float4* p = (const float4*)(w + w1off + ut * 128 + kg * 8 + k * 32);
        bf16x8 bf = pack8(p[0], p[1]);
        acc = __builtin_amdgcn_mfma_f32_16x16x32_bf16(a4[k], bf, acc, 0, 0, 0);
      }
#pragma unroll
      for (int r = 0; r < 4; r++)   // row = b = kg*4+r, col = u
        mixed1[(kg * 4 + r) * TPAD + (wid * 2 + ti) * 16 + l16] = acc[r];
    }
    __syncthreads();   // mixed1 visible to all lanes before epilogue reads
  }

  // ---- per-ti: W0 frags, x1 row chunk, mode0 register dot, epilogues
#pragma unroll
  for (int ti = 0; ti < 2; ti++) {
    const int ut = (wid * 2 + ti) * 16 + l16;     // A-operand m row = u
    const int u0 = (wid * 2 + ti) * 16 + kg * 4;  // lane's first output u

    bf16x8 w0f[4];
#pragma unroll
    for (int k = 0; k < 4; k++) {
      const float4* p = (const float4*)(w + w0off + ut * 128 + kg * 8 + k * 32);
      w0f[k] = pack8(p[0], p[1]);
    }

    // x1 chunk for this lane: x1[b0+l16, rs + u0*D .. u0*D+4D) — contiguous floats
    const float* xrow = x1 + (size_t)(b0 + l16) * IN_DIM + rs + u0 * D;
    float xv[4 * D];
#pragma unroll
    for (int n = 0; n < 4 * D; n++) xv[n] = xrow[n];

    // mode0: per dd, MFMA chain then register dot (no barriers)
    f32x4 m0acc = {0.f, 0.f, 0.f, 0.f};
#pragma unroll
    for (int dd = 0; dd < D; dd++) {
      bf16x8 bfr[4];
#pragma unroll
      for (int k = 0; k < 4; k++)
        bfr[k] = *(const bf16x8*)&x2s[dd * PLANE + l16 * SROW + kg * 8 + k * 32];
      f32x4 acc = {0.f, 0.f, 0.f, 0.f};
#pragma unroll
      for (int k = 0; k < 4; k++)
        acc = __builtin_amdgcn_mfma_f32_16x16x32_bf16(w0f[k], bfr[k], acc, 0, 0, 0);
      // acc[r] = tmp[u = u0+r][b = l16] for this dd (same mapping v1's tmp verified)
#pragma unroll
      for (int r = 0; r < 4; r++)
        m0acc[r] += acc[r] * xv[r * D + dd];
    }

    const size_t orow = (size_t)(b0 + l16) * OUT_DIM;

    // mode0 epilogue: out[b, outs0 + u0 + r] (4 consecutive floats, compiler-merged)
#pragma unroll
    for (int r = 0; r < 4; r++)
      out[orow + outs0 + u0 + r] = m0acc[r] * inv * mask[outs0 + u0 + r];

    // mode1 epilogue: out[b, outs1 + (u0+r)*D + dd] = x1v * mixed1[b][u0+r] * inv * mask
    // (4D consecutive floats per lane, compiler-merged; xv reused from registers)
    if (HASM1) {
#pragma unroll
      for (int r = 0; r < 4; r++) {
        float m1 = mixed1[l16 * TPAD + u0 + r];
#pragma unroll
        for (int dd = 0; dd < D; dd++) {
          int col = outs1 + (u0 + r) * D + dd;
          out[orow + col] = xv[r * D + dd] * m1 * inv * mask[col];
        }
      }
    }
  }
}

__global__ void __launch_bounds__(256, 3)
tp_kernel(const float* __restrict__ x1, const float* __restrict__ x2,
          const float* __restrict__ w, const float* __restrict__ mask,
          float* __restrict__ out)
{
  __shared__ __align__(16) short x2s[7 * PLANE];    // 30.6 KB
  __shared__ __align__(16) short scal[TB * SROW];   //  4.4 KB
  __shared__ __align__(16) float mixed1[TB * TPAD]; //  8.3 KB  -> 43.2 KB total

  int bx   = blockIdx.x;
  int g    = bx & 3;        // interleave groups for L2 reuse of x2[:, :128]
  int tile = bx >> 2;

  switch (g) {
    case 0:
      run_group<1, false>(x1, x2, w, mask, out, tile, 0, 0, 0 * 16384, 0, 0,
                          1.0f, x2s, scal, mixed1);
      break;
    case 1:
      run_group<3, true>(x1, x2, w, mask, out, tile, 128, 128, 1 * 16384, 512, 4 * 16384,
                         0.5773502691896258f, x2s, scal, mixed1);
      break;
    case 2:
      run_group<5, true>(x1, x2, w, mask, out, tile, 512, 256, 2 * 16384, 896, 5 * 16384,
                         0.4472135954999579f, x2s, scal, mixed1);
      break;
    case 3:
      run_group<7, true>(x1, x2, w, mask, out, tile, 1152, 384, 3 * 16384, 1536, 6 * 16384,
                         0.3779644730092272f, x2s, scal, mixed1);
      break;
  }
}

extern "C" void kernel_launch(void* const* d_in, const int* in_sizes, int n_in,
                              void* d_out, int out_size, void* d_ws, size_t ws_size,
                              hipStream_t stream) {
  const float* x1   = (const float*)d_in[0];
  const float* x2   = (const float*)d_in[1];
  const float* w    = (const float*)d_in[2];
  const float* mask = (const float*)d_in[3];
  float* out = (float*)d_out;

  dim3 grid(4 * (32768 / TB));  // 8192 blocks: (tile, group) interleaved
  dim3 block(256);
  tp_kernel<<<grid, block, 0, stream>>>(x1, x2, w, mask, out);
}